// Round 14
// baseline (670.761 us; speedup 1.0000x reference)
//
#include <hip/hip_runtime.h>
#include <stdint.h>

// EAM force: index-CSR binning + SPLIT gather/reduce phases.
//
// HW model (r3-r13): global fp atomics ~20.5G/s chip-wide -> use none.
// Slab-resident acc kernels pinned at 5-11 cyc/record invariant to occupancy/
// ILP/XCD-replication/scalar-tables; r8's slab-free bin kernels did scattered
// work ~4x faster. This round: gather+compute kernels carry NO LDS (write
// values coalesced); reduce kernels do LDS slab accumulate with NO gathers.

#define BLK     256
#define BLKA    512
#define SHIFT   10
#define BSZ     1024
#define NBPAD   256
#define SSTRIPS 16
#define PPB_B   4096

__device__ __forceinline__ float interp_row(const float* __restrict__ row,
                                            int i0, int i1, float fr) {
    float a = row[i0];
    float b = row[i1];
    return a + fr * (b - a);
}

__device__ __forceinline__ float embed_dF_f(float rho, int t,
                                            const float* __restrict__ embed_tab,
                                            const float* __restrict__ rho_min_t,
                                            const float* __restrict__ inv_drho_t,
                                            int n_rho, float one_m_eps) {
    float rmin = rho_min_t[t];
    float invd = inv_drho_t[t];
    float hi = rmin + (float)(n_rho - 1) / invd * one_m_eps;
    float rc = fminf(fmaxf(rho, rmin), hi);
    float g  = (rc - rmin) * invd;
    int  g0  = (int)g;
    g0 = g0 < 0 ? 0 : (g0 > n_rho - 2 ? n_rho - 2 : g0);
    float gfr = g - (float)g0;
    const float* row = embed_tab + (size_t)t * n_rho;
    float e0 = row[g0];
    float e1 = row[g0 + 1];
    return e0 + gfr * (e1 - e0);
}

__device__ __forceinline__ void geom_own(
    float xo, float yo, float zo,
    float xw, float yw, float zw,
    float inv_dr, float rclip, int n_r,
    float& dx, float& dy, float& dz, float& r,
    int& i0, int& i1, float& fr)
{
#pragma clang fp contract(off)
    dx = xo - xw; dy = yo - yw; dz = zo - zw;
    float s = dx * dx;
    s = s + dy * dy;
    s = s + dz * dz;
    s = s + 1e-12f;
    r = sqrtf(s);
    float rc = fminf(fmaxf(r, 0.0f), rclip);
    float f  = rc * inv_dr;
    i0 = (int)f;
    fr = f - (float)i0;
    i1 = min(i0 + 1, n_r - 1);
}

// ---------------- meta ----------------

__global__ void eam_zero_meta(int* __restrict__ counts) {
    counts[threadIdx.x] = 0;
}

__global__ void eam_count(const int* __restrict__ ei, const int* __restrict__ ej,
                          int P, int* __restrict__ counts)
{
    __shared__ int cnt[NBPAD];
    for (int k = threadIdx.x; k < NBPAD; k += BLK) cnt[k] = 0;
    __syncthreads();
    for (int p = blockIdx.x * BLK + threadIdx.x; p < P; p += gridDim.x * BLK) {
        atomicAdd(&cnt[((unsigned)ei[p]) >> SHIFT], 1);
        atomicAdd(&cnt[((unsigned)ej[p]) >> SHIFT], 1);
    }
    __syncthreads();
    for (int k = threadIdx.x; k < NBPAD; k += BLK)
        if (cnt[k]) atomicAdd(&counts[k], cnt[k]);
}

__global__ void eam_scan(const int* __restrict__ counts,
                         int* __restrict__ base, int* __restrict__ cur)
{
    __shared__ int s[NBPAD];
    int t = threadIdx.x;
    int c = counts[t];
    s[t] = c;
    __syncthreads();
    for (int d = 1; d < NBPAD; d <<= 1) {
        int v = (t >= d) ? s[t - d] : 0;
        __syncthreads();
        s[t] += v;
        __syncthreads();
    }
    base[t] = s[t] - c;
    cur[t]  = s[t] - c;
}

__global__ void eam_build_pos4t(const float* __restrict__ pos,
                                const int* __restrict__ types,
                                float4* __restrict__ pos4t, int N)
{
    int n = blockIdx.x * blockDim.x + threadIdx.x;
    if (n >= N) return;
    float4 v;
    v.x = pos[3 * n + 0];
    v.y = pos[3 * n + 1];
    v.z = pos[3 * n + 2];
    v.w = __int_as_float(types[n]);
    pos4t[n] = v;
}

// ---------------- bin: directed index records ----------------

__global__ __launch_bounds__(BLK) void eam_bin(
    const int* __restrict__ ei, const int* __restrict__ ej, int P,
    int* __restrict__ cur_glob, unsigned* __restrict__ recs)
{
    __shared__ int cnt[NBPAD], off[NBPAD], curs[NBPAD], gb[NBPAD], sc[NBPAD];
    __shared__ unsigned sR[2 * PPB_B];
    __shared__ unsigned char sB[2 * PPB_B];
    const int tid = threadIdx.x;
    const long long p0 = (long long)blockIdx.x * PPB_B;
    const int pend = (int)((p0 + PPB_B < (long long)P) ? p0 + PPB_B : (long long)P);

    for (int k = tid; k < NBPAD; k += BLK) cnt[k] = 0;
    __syncthreads();

    for (int p = (int)p0 + tid; p < pend; p += BLK) {
        atomicAdd(&cnt[((unsigned)ei[p]) >> SHIFT], 1);
        atomicAdd(&cnt[((unsigned)ej[p]) >> SHIFT], 1);
    }
    __syncthreads();

    int c = cnt[tid];
    sc[tid] = c;
    __syncthreads();
    for (int d = 1; d < NBPAD; d <<= 1) {
        int v = (tid >= d) ? sc[tid - d] : 0;
        __syncthreads();
        sc[tid] += v;
        __syncthreads();
    }
    off[tid] = sc[tid] - c;
    curs[tid] = off[tid];
    if (c > 0) gb[tid] = atomicAdd(&cur_glob[tid], c);
    __syncthreads();

    for (int p = (int)p0 + tid; p < pend; p += BLK) {
        unsigned i = (unsigned)ei[p];
        unsigned j = (unsigned)ej[p];
        int bi = i >> SHIFT;
        int sl = atomicAdd(&curs[bi], 1);
        sR[sl] = j | ((i & (BSZ - 1)) << 20) | (1u << 30);  // owner=i
        sB[sl] = (unsigned char)bi;
        int bj = j >> SHIFT;
        sl = atomicAdd(&curs[bj], 1);
        sR[sl] = i | ((j & (BSZ - 1)) << 20);               // owner=j
        sB[sl] = (unsigned char)bj;
    }
    __syncthreads();

    int total = off[NBPAD - 1] + cnt[NBPAD - 1];
    for (int q = tid; q < total; q += BLK) {
        int b = sB[q];
        int dst = gb[b] + (q - off[b]);
        recs[dst] = sR[q];
    }
}

// ---------------- gather rho (no LDS, coalesced value writes) ----------------

__global__ __launch_bounds__(BLKA) void eam_gather_rho(
    const unsigned* __restrict__ recs,
    const int* __restrict__ base, const int* __restrict__ counts,
    const float4* __restrict__ pos4t,
    const float* __restrict__ dens_tab, int n_r, int E,
    float inv_dr, float rclip,
    float* __restrict__ val, int N)
{
    const int b = blockIdx.x / SSTRIPS;
    const int s = blockIdx.x % SSTRIPS;
    const int abase = b << SHIFT;

    int cb = counts[b];
    int e0 = base[b] + (int)(((long long)cb * s) / SSTRIPS);
    int e1 = base[b] + (int)(((long long)cb * (s + 1)) / SSTRIPS);

    for (int q = e0 + threadIdx.x; q < e1; q += BLKA) {
        unsigned rec = recs[q];
        int other = rec & 0xFFFFF;
        int low = (rec >> 20) & (BSZ - 1);
        float4 o = pos4t[other];           // cold scattered
        float4 w = pos4t[abase + low];     // L1-hot (16KB window)
        float dx, dy, dz, r, fr; int i0, i1;
        geom_own(o.x, o.y, o.z, w.x, w.y, w.z, inv_dr, rclip, n_r,
                 dx, dy, dz, r, i0, i1, fr);
        int t_oth = __float_as_int(o.w);

        float v;
        int i0u = __builtin_amdgcn_readfirstlane(i0);
        if (E == 2 && __all(i0 == i0u)) {
            int s1 = min(i0u + 1, n_r - 1);
            float b00 = dens_tab[i0u], b01 = dens_tab[s1];
            float b10 = dens_tab[n_r + i0u], b11 = dens_tab[n_r + s1];
            float e0v = t_oth ? b10 : b00;
            float e1v = t_oth ? b11 : b01;
            v = e0v + fr * (e1v - e0v);
        } else {
            v = interp_row(dens_tab + (size_t)t_oth * n_r, i0, i1, fr);
        }
        val[q] = v;                        // coalesced write
    }
}

// ---------------- reduce rho (LDS slab, no gathers) ----------------

__global__ __launch_bounds__(BLKA) void eam_reduce_rho_slab(
    const unsigned* __restrict__ recs, const float* __restrict__ val,
    const int* __restrict__ base, const int* __restrict__ counts,
    float* __restrict__ partial)
{
    __shared__ float slab[BSZ];
    const int tid = threadIdx.x;
    const int b = blockIdx.x / SSTRIPS;
    const int s = blockIdx.x % SSTRIPS;

    for (int k = tid; k < BSZ; k += BLKA) slab[k] = 0.f;
    __syncthreads();

    int cb = counts[b];
    int e0 = base[b] + (int)(((long long)cb * s) / SSTRIPS);
    int e1 = base[b] + (int)(((long long)cb * (s + 1)) / SSTRIPS);

    for (int q = e0 + tid; q < e1; q += BLKA) {
        int low = (recs[q] >> 20) & (BSZ - 1);
        atomicAdd(&slab[low], val[q]);
    }
    __syncthreads();

    float* out = partial + ((size_t)(b * SSTRIPS + s) << SHIFT);
    for (int k = tid; k < BSZ; k += BLKA) out[k] = slab[k];
}

// rho = sum strips; dF = F'(rho); pos4f = (x,y,z, dF|type2LSB)
__global__ void eam_reduce_rho_embed_pack(
    const float* __restrict__ partial, const float* __restrict__ pos,
    const int* __restrict__ types,
    const float* __restrict__ embed_tab,
    const float* __restrict__ rho_min_t, const float* __restrict__ inv_drho_t,
    int n_rho, float one_m_eps, float4* __restrict__ pos4f, int N)
{
    int n = blockIdx.x * blockDim.x + threadIdx.x;
    if (n >= N) return;
    int b = n >> SHIFT;
    int low = n & (BSZ - 1);
    float rho = 0.f;
#pragma unroll
    for (int s = 0; s < SSTRIPS; ++s)
        rho += partial[((size_t)(b * SSTRIPS + s) << SHIFT) + low];
    int t = types[n];
    float dF = embed_dF_f(rho, t, embed_tab, rho_min_t, inv_drho_t,
                          n_rho, one_m_eps);
    unsigned u = (__float_as_uint(dF) & ~3u) | ((unsigned)t & 3u);
    float4 v;
    v.x = pos[3 * n + 0];
    v.y = pos[3 * n + 1];
    v.z = pos[3 * n + 2];
    v.w = __uint_as_float(u);
    pos4f[n] = v;
}

// ---------------- gather force (no LDS, coalesced fvec writes) ----------------

__global__ __launch_bounds__(BLKA) void eam_gather_force(
    const unsigned* __restrict__ recs,
    const int* __restrict__ base, const int* __restrict__ counts,
    const float4* __restrict__ pos4f,
    const float* __restrict__ dens_deriv_tab,
    const float* __restrict__ pair_deriv_tab,
    int n_r, int E, float inv_dr, float rclip,
    int bstart, long long cap,
    float* __restrict__ fxv, float* __restrict__ fyv, float* __restrict__ fzv)
{
    const int b = bstart + blockIdx.x / SSTRIPS;
    const int s = blockIdx.x % SSTRIPS;
    const int abase = b << SHIFT;
    const int vbase = base[bstart];

    int cb = counts[b];
    int e0 = base[b] + (int)(((long long)cb * s) / SSTRIPS);
    int e1 = base[b] + (int)(((long long)cb * (s + 1)) / SSTRIPS);

    for (int q = e0 + threadIdx.x; q < e1; q += BLKA) {
        unsigned rec = recs[q];
        int other  = rec & 0xFFFFF;
        int low    = (rec >> 20) & (BSZ - 1);
        int orient = (rec >> 30) & 1;

        float4 o = pos4f[other];           // cold scattered
        float4 w = pos4f[abase + low];     // L1-hot
        int t_oth = (int)(__float_as_uint(o.w) & 3u);
        int t_own = (int)(__float_as_uint(w.w) & 3u);

        float dx, dy, dz, r, fr; int i0, i1;
        geom_own(o.x, o.y, o.z, w.x, w.y, w.z, inv_dr, rclip, n_r,
                 dx, dy, dz, r, i0, i1, fr);

        int prow = orient ? (t_own * E + t_oth) : (t_oth * E + t_own);

        float ddens_oth, ddens_own, dphi;
        int i0u = __builtin_amdgcn_readfirstlane(i0);
        if (E == 2 && __all(i0 == i0u)) {
            int s1 = min(i0u + 1, n_r - 1);
            float a00 = dens_deriv_tab[i0u],       a01 = dens_deriv_tab[s1];
            float a10 = dens_deriv_tab[n_r + i0u], a11 = dens_deriv_tab[n_r + s1];
            float e0o = t_oth ? a10 : a00;
            float e1o = t_oth ? a11 : a01;
            ddens_oth = e0o + fr * (e1o - e0o);
            float e0w = t_own ? a10 : a00;
            float e1w = t_own ? a11 : a01;
            ddens_own = e0w + fr * (e1w - e0w);

            float p00 = pair_deriv_tab[i0u],           p01 = pair_deriv_tab[s1];
            float p10 = pair_deriv_tab[n_r + i0u],     p11 = pair_deriv_tab[n_r + s1];
            float p20 = pair_deriv_tab[2 * n_r + i0u], p21 = pair_deriv_tab[2 * n_r + s1];
            float p30 = pair_deriv_tab[3 * n_r + i0u], p31 = pair_deriv_tab[3 * n_r + s1];
            float q0 = (prow & 2) ? ((prow & 1) ? p30 : p20)
                                  : ((prow & 1) ? p10 : p00);
            float q1 = (prow & 2) ? ((prow & 1) ? p31 : p21)
                                  : ((prow & 1) ? p11 : p01);
            dphi = q0 + fr * (q1 - q0);
        } else {
            ddens_oth = interp_row(dens_deriv_tab + (size_t)t_oth * n_r, i0, i1, fr);
            ddens_own = interp_row(dens_deriv_tab + (size_t)t_own * n_r, i0, i1, fr);
            dphi      = interp_row(pair_deriv_tab + (size_t)prow * n_r, i0, i1, fr);
        }

        float coeff = w.w * ddens_oth + o.w * ddens_own + dphi;

        long long idx = (long long)q - vbase;
        if (idx >= 0 && idx < cap) {
            fxv[idx] = -(coeff * (dx / r));
            fyv[idx] = -(coeff * (dy / r));
            fzv[idx] = -(coeff * (dz / r));
        }
    }
}

// ---------------- reduce force (LDS slab, no gathers) ----------------

__global__ __launch_bounds__(BLKA) void eam_reduce_force_slab(
    const unsigned* __restrict__ recs,
    const float* __restrict__ fxv, const float* __restrict__ fyv,
    const float* __restrict__ fzv,
    const int* __restrict__ base, const int* __restrict__ counts,
    int bstart, long long cap,
    float* __restrict__ partial)
{
    __shared__ float slab[3 * BSZ];
    const int tid = threadIdx.x;
    const int b = bstart + blockIdx.x / SSTRIPS;
    const int s = blockIdx.x % SSTRIPS;
    const int vbase = base[bstart];

    for (int k = tid; k < 3 * BSZ; k += BLKA) slab[k] = 0.f;
    __syncthreads();

    int cb = counts[b];
    int e0 = base[b] + (int)(((long long)cb * s) / SSTRIPS);
    int e1 = base[b] + (int)(((long long)cb * (s + 1)) / SSTRIPS);

    for (int q = e0 + tid; q < e1; q += BLKA) {
        int low = (recs[q] >> 20) & (BSZ - 1);
        long long idx = (long long)q - vbase;
        if (idx >= 0 && idx < cap) {
            atomicAdd(&slab[low * 3 + 0], fxv[idx]);
            atomicAdd(&slab[low * 3 + 1], fyv[idx]);
            atomicAdd(&slab[low * 3 + 2], fzv[idx]);
        }
    }
    __syncthreads();

    float* out = partial + (size_t)(b * SSTRIPS + s) * (3 * BSZ);
    for (int k = tid; k < 3 * BSZ; k += BLKA) out[k] = slab[k];
}

__global__ void eam_reduce_force(const float* __restrict__ partial,
                                 float* __restrict__ forces, int N)
{
    int idx = blockIdx.x * blockDim.x + threadIdx.x;
    if (idx >= 3 * N) return;
    int a = idx / 3;
    int comp = idx - 3 * a;
    int b = a >> SHIFT;
    int low = a & (BSZ - 1);
    float s = 0.f;
#pragma unroll
    for (int k = 0; k < SSTRIPS; ++k)
        s += partial[(size_t)(b * SSTRIPS + k) * (3 * BSZ) + low * 3 + comp];
    forces[idx] = s;
}

// ---------------- fallback: direct agent-atomic path ----------------

__device__ __forceinline__ void pair_geom(
    const float* __restrict__ pos, int i, int j,
    float inv_dr, float rclip,
    float& dx, float& dy, float& dz, float& r,
    int& i0, int& i1, float& fr, int n_r)
{
#pragma clang fp contract(off)
    float xi = pos[3 * i + 0], yi = pos[3 * i + 1], zi = pos[3 * i + 2];
    float xj = pos[3 * j + 0], yj = pos[3 * j + 1], zj = pos[3 * j + 2];
    dx = xj - xi; dy = yj - yi; dz = zj - zi;
    float s = dx * dx;
    s = s + dy * dy;
    s = s + dz * dz;
    s = s + 1e-12f;
    r = sqrtf(s);
    float rc = fminf(fmaxf(r, 0.0f), rclip);
    float f  = rc * inv_dr;
    i0 = (int)f;
    fr = f - (float)i0;
    i1 = min(i0 + 1, n_r - 1);
}

__global__ void eam_zero_rho_forces(float* __restrict__ rho,
                                    float* __restrict__ forces, int N) {
    int idx = blockIdx.x * blockDim.x + threadIdx.x;
    if (idx < N) rho[idx] = 0.0f;
    if (idx < 3 * N) forces[idx] = 0.0f;
}

__global__ void eam_density_direct(
    const int* __restrict__ ei, const int* __restrict__ ej,
    const int* __restrict__ types, const float* __restrict__ pos,
    const float* __restrict__ dens_tab, int n_r, float inv_dr, float rclip,
    float* __restrict__ rho, int P)
{
    int p = blockIdx.x * blockDim.x + threadIdx.x;
    if (p >= P) return;
    int i = ei[p], j = ej[p];
    float dx, dy, dz, r, fr; int i0, i1;
    pair_geom(pos, i, j, inv_dr, rclip, dx, dy, dz, r, i0, i1, fr, n_r);
    int ti = types[i], tj = types[j];
    unsafeAtomicAdd(&rho[i], interp_row(dens_tab + (size_t)tj * n_r, i0, i1, fr));
    unsafeAtomicAdd(&rho[j], interp_row(dens_tab + (size_t)ti * n_r, i0, i1, fr));
}

__global__ void eam_force_direct(
    const int* __restrict__ ei, const int* __restrict__ ej,
    const int* __restrict__ types, const float* __restrict__ pos,
    const float* __restrict__ dens_deriv_tab,
    const float* __restrict__ pair_deriv_tab,
    const float* __restrict__ rho,
    const float* __restrict__ embed_tab,
    const float* __restrict__ rho_min_t, const float* __restrict__ inv_drho_t,
    int n_r, int n_rho, int E, float inv_dr, float rclip, float one_m_eps,
    float* __restrict__ forces, int P)
{
    int p = blockIdx.x * blockDim.x + threadIdx.x;
    if (p >= P) return;
    int i = ei[p], j = ej[p];
    float dx, dy, dz, r, fr; int i0, i1;
    pair_geom(pos, i, j, inv_dr, rclip, dx, dy, dz, r, i0, i1, fr, n_r);
    int ti = types[i], tj = types[j];
    float ddens_j = interp_row(dens_deriv_tab + (size_t)tj * n_r, i0, i1, fr);
    float ddens_i = interp_row(dens_deriv_tab + (size_t)ti * n_r, i0, i1, fr);
    float dphi    = interp_row(pair_deriv_tab + ((size_t)ti * E + tj) * n_r, i0, i1, fr);
    float dFi = embed_dF_f(rho[i], ti, embed_tab, rho_min_t, inv_drho_t, n_rho, one_m_eps);
    float dFj = embed_dF_f(rho[j], tj, embed_tab, rho_min_t, inv_drho_t, n_rho, one_m_eps);
    float coeff = dFi * ddens_j + dFj * ddens_i + dphi;
    float fxv = coeff * (dx / r), fyv = coeff * (dy / r), fzv = coeff * (dz / r);
    unsafeAtomicAdd(&forces[3 * i + 0], -fxv);
    unsafeAtomicAdd(&forces[3 * i + 1], -fyv);
    unsafeAtomicAdd(&forces[3 * i + 2], -fzv);
    unsafeAtomicAdd(&forces[3 * j + 0],  fxv);
    unsafeAtomicAdd(&forces[3 * j + 1],  fyv);
    unsafeAtomicAdd(&forces[3 * j + 2],  fzv);
}

// ---------------- launcher ----------------

extern "C" void kernel_launch(void* const* d_in, const int* in_sizes, int n_in,
                              void* d_out, int out_size, void* d_ws, size_t ws_size,
                              hipStream_t stream) {
    const float* positions      = (const float*)d_in[0];
    const float* density_table  = (const float*)d_in[1];
    const float* density_deriv  = (const float*)d_in[2];
    const float* pair_deriv     = (const float*)d_in[3];
    const float* embed_deriv    = (const float*)d_in[4];
    const float* embed_rho_min  = (const float*)d_in[5];
    const float* embed_inv_drho = (const float*)d_in[6];
    const int*   atom_types     = (const int*)d_in[7];
    const int*   edge_i         = (const int*)d_in[8];
    const int*   edge_j         = (const int*)d_in[9];

    const int E     = in_sizes[5];
    const int N     = in_sizes[7];
    const int P     = in_sizes[8];
    const int n_r   = in_sizes[1] / E;
    const int n_rho = in_sizes[4] / E;

    const double R_MAX_d = 6.0;
    const double EPS_d   = 1e-7;
    const float inv_dr    = (float)((double)(n_r - 1) / R_MAX_d);
    const float rclip     = (float)(R_MAX_d * (1.0 - EPS_d));
    const float one_m_eps = (float)(1.0 - EPS_d);

    float* forces = (float*)d_out;

    const int NB = (N + BSZ - 1) >> SHIFT;
    const long long cap = (long long)P + (1 << 17);  // half-chunk records + 36 sigma

    // ws: counts|base|cur | pos4t[N] | pos4f[N] | partials | recs[2P] | vals[3*cap]
    char* wp = (char*)d_ws;
    int* counts = (int*)wp;  wp += NBPAD * sizeof(int);
    int* base   = (int*)wp;  wp += NBPAD * sizeof(int);
    int* cur    = (int*)wp;  wp += NBPAD * sizeof(int);
    wp = (char*)(((uintptr_t)wp + 255) & ~(uintptr_t)255);
    float4* pos4t = (float4*)wp; wp += (size_t)N * sizeof(float4);
    float4* pos4f = (float4*)wp; wp += (size_t)N * sizeof(float4);
    float* partials = (float*)wp; wp += (size_t)NB * SSTRIPS * 3 * BSZ * sizeof(float);
    unsigned* recs = (unsigned*)wp; wp += 2 * (size_t)P * sizeof(unsigned);
    float* vals = (float*)wp; wp += 3 * (size_t)cap * sizeof(float);
    const size_t need = (size_t)(wp - (char*)d_ws);

    const int pair_blocks = (P + BLK - 1) / BLK;
    const int atom_blocks = (N + BLK - 1) / BLK;

    if (need > ws_size || NB > NBPAD || N >= (1 << 20) || E > 4) {
        float* rho_f = (float*)d_ws;
        eam_zero_rho_forces<<<(3 * N + BLK - 1) / BLK, BLK, 0, stream>>>(rho_f, forces, N);
        eam_density_direct<<<pair_blocks, BLK, 0, stream>>>(
            edge_i, edge_j, atom_types, positions,
            density_table, n_r, inv_dr, rclip, rho_f, P);
        eam_force_direct<<<pair_blocks, BLK, 0, stream>>>(
            edge_i, edge_j, atom_types, positions,
            density_deriv, pair_deriv, rho_f,
            embed_deriv, embed_rho_min, embed_inv_drho,
            n_r, n_rho, E, inv_dr, rclip, one_m_eps, forces, P);
        return;
    }

    float* valR = vals;            // rho values: 2P floats <= 3*cap
    float* fxv = vals;             // force chunks reuse the same region
    float* fyv = vals + cap;
    float* fzv = vals + 2 * cap;

    eam_zero_meta<<<1, NBPAD, 0, stream>>>(counts);
    eam_count<<<512, BLK, 0, stream>>>(edge_i, edge_j, P, counts);
    eam_scan<<<1, NBPAD, 0, stream>>>(counts, base, cur);
    eam_build_pos4t<<<atom_blocks, BLK, 0, stream>>>(positions, atom_types, pos4t, N);

    eam_bin<<<(P + PPB_B - 1) / PPB_B, BLK, 0, stream>>>(
        edge_i, edge_j, P, cur, recs);

    // rho: gather -> reduce (unchunked; 2P floats fit in vals region)
    eam_gather_rho<<<NB * SSTRIPS, BLKA, 0, stream>>>(
        recs, base, counts, pos4t,
        density_table, n_r, E, inv_dr, rclip, valR, N);
    eam_reduce_rho_slab<<<NB * SSTRIPS, BLKA, 0, stream>>>(
        recs, valR, base, counts, partials);

    eam_reduce_rho_embed_pack<<<atom_blocks, BLK, 0, stream>>>(
        partials, positions, atom_types,
        embed_deriv, embed_rho_min, embed_inv_drho,
        n_rho, one_m_eps, pos4f, N);

    // force: 2 bucket-range chunks sharing the vals region
    const int bmid = NB / 2;
    const int chunks[2][2] = { {0, bmid}, {bmid, NB} };
    for (int c = 0; c < 2; ++c) {
        int b0 = chunks[c][0], b1 = chunks[c][1];
        int nbc = b1 - b0;
        if (nbc <= 0) continue;
        eam_gather_force<<<nbc * SSTRIPS, BLKA, 0, stream>>>(
            recs, base, counts, pos4f,
            density_deriv, pair_deriv,
            n_r, E, inv_dr, rclip, b0, cap, fxv, fyv, fzv);
        eam_reduce_force_slab<<<nbc * SSTRIPS, BLKA, 0, stream>>>(
            recs, fxv, fyv, fzv, base, counts, b0, cap, partials);
    }

    eam_reduce_force<<<(3 * N + BLK - 1) / BLK, BLK, 0, stream>>>(
        partials, forces, N);
}

// Round 15
// 427.690 us; speedup vs baseline: 1.5683x; 1.5683x over previous
//
#include <hip/hip_runtime.h>
#include <stdint.h>

// EAM force via index-only CSR binning + single-float4 gathers +
// wave-uniform scalar table loads + NATIVE LDS fp atomics.
//
// HW model: (r3-r7) global fp atomics ~20.5G/s chip-wide -> use none.
// (r14 split experiment): slab accumulate WITHOUT gathers costs the same
// 228us as the full fused kernel -> LDS float atomicAdd is the wall at
// ~10.7 cyc/lane. Diagnosis: HIP lowers shared-memory float atomicAdd to a
// CAS retry loop (native ds_add_f32 needs unsafe-fp-atomics). Fix:
// unsafeAtomicAdd on the slab -> ds_add_f32 (no return, no retry).

#define BLK     256
#define BLKA    512
#define SHIFT   10
#define BSZ     1024
#define NBPAD   256
#define SSTRIPS 16
#define PPB_B   4096

__device__ __forceinline__ void lds_fadd(float* p, float v) {
    unsafeAtomicAdd(p, v);   // ds_add_f32 on LDS pointers
}

__device__ __forceinline__ float interp_row(const float* __restrict__ row,
                                            int i0, int i1, float fr) {
    float a = row[i0];
    float b = row[i1];
    return a + fr * (b - a);
}

__device__ __forceinline__ float embed_dF_f(float rho, int t,
                                            const float* __restrict__ embed_tab,
                                            const float* __restrict__ rho_min_t,
                                            const float* __restrict__ inv_drho_t,
                                            int n_rho, float one_m_eps) {
    float rmin = rho_min_t[t];
    float invd = inv_drho_t[t];
    float hi = rmin + (float)(n_rho - 1) / invd * one_m_eps;
    float rc = fminf(fmaxf(rho, rmin), hi);
    float g  = (rc - rmin) * invd;
    int  g0  = (int)g;
    g0 = g0 < 0 ? 0 : (g0 > n_rho - 2 ? n_rho - 2 : g0);
    float gfr = g - (float)g0;
    const float* row = embed_tab + (size_t)t * n_rho;
    float e0 = row[g0];
    float e1 = row[g0 + 1];
    return e0 + gfr * (e1 - e0);
}

__device__ __forceinline__ void geom_own(
    float xo, float yo, float zo,
    float xw, float yw, float zw,
    float inv_dr, float rclip, int n_r,
    float& dx, float& dy, float& dz, float& r,
    int& i0, int& i1, float& fr)
{
#pragma clang fp contract(off)
    dx = xo - xw; dy = yo - yw; dz = zo - zw;
    float s = dx * dx;
    s = s + dy * dy;
    s = s + dz * dz;
    s = s + 1e-12f;
    r = sqrtf(s);
    float rc = fminf(fmaxf(r, 0.0f), rclip);
    float f  = rc * inv_dr;
    i0 = (int)f;
    fr = f - (float)i0;
    i1 = min(i0 + 1, n_r - 1);
}

// ---------------- meta ----------------

__global__ void eam_zero_meta(int* __restrict__ counts) {
    counts[threadIdx.x] = 0;
}

__global__ void eam_count(const int* __restrict__ ei, const int* __restrict__ ej,
                          int P, int* __restrict__ counts)
{
    __shared__ int cnt[NBPAD];
    for (int k = threadIdx.x; k < NBPAD; k += BLK) cnt[k] = 0;
    __syncthreads();
    for (int p = blockIdx.x * BLK + threadIdx.x; p < P; p += gridDim.x * BLK) {
        atomicAdd(&cnt[((unsigned)ei[p]) >> SHIFT], 1);
        atomicAdd(&cnt[((unsigned)ej[p]) >> SHIFT], 1);
    }
    __syncthreads();
    for (int k = threadIdx.x; k < NBPAD; k += BLK)
        if (cnt[k]) atomicAdd(&counts[k], cnt[k]);
}

__global__ void eam_scan(const int* __restrict__ counts,
                         int* __restrict__ base, int* __restrict__ cur)
{
    __shared__ int s[NBPAD];
    int t = threadIdx.x;
    int c = counts[t];
    s[t] = c;
    __syncthreads();
    for (int d = 1; d < NBPAD; d <<= 1) {
        int v = (t >= d) ? s[t - d] : 0;
        __syncthreads();
        s[t] += v;
        __syncthreads();
    }
    base[t] = s[t] - c;
    cur[t]  = s[t] - c;
}

__global__ void eam_build_pos4t(const float* __restrict__ pos,
                                const int* __restrict__ types,
                                float4* __restrict__ pos4t, int N)
{
    int n = blockIdx.x * blockDim.x + threadIdx.x;
    if (n >= N) return;
    float4 v;
    v.x = pos[3 * n + 0];
    v.y = pos[3 * n + 1];
    v.z = pos[3 * n + 2];
    v.w = __int_as_float(types[n]);
    pos4t[n] = v;
}

// ---------------- bin: directed index records ----------------

__global__ __launch_bounds__(BLK) void eam_bin(
    const int* __restrict__ ei, const int* __restrict__ ej, int P,
    int* __restrict__ cur_glob, unsigned* __restrict__ recs)
{
    __shared__ int cnt[NBPAD], off[NBPAD], curs[NBPAD], gb[NBPAD], sc[NBPAD];
    __shared__ unsigned sR[2 * PPB_B];
    __shared__ unsigned char sB[2 * PPB_B];
    const int tid = threadIdx.x;
    const long long p0 = (long long)blockIdx.x * PPB_B;
    const int pend = (int)((p0 + PPB_B < (long long)P) ? p0 + PPB_B : (long long)P);

    for (int k = tid; k < NBPAD; k += BLK) cnt[k] = 0;
    __syncthreads();

    for (int p = (int)p0 + tid; p < pend; p += BLK) {
        atomicAdd(&cnt[((unsigned)ei[p]) >> SHIFT], 1);
        atomicAdd(&cnt[((unsigned)ej[p]) >> SHIFT], 1);
    }
    __syncthreads();

    int c = cnt[tid];
    sc[tid] = c;
    __syncthreads();
    for (int d = 1; d < NBPAD; d <<= 1) {
        int v = (tid >= d) ? sc[tid - d] : 0;
        __syncthreads();
        sc[tid] += v;
        __syncthreads();
    }
    off[tid] = sc[tid] - c;
    curs[tid] = off[tid];
    if (c > 0) gb[tid] = atomicAdd(&cur_glob[tid], c);
    __syncthreads();

    for (int p = (int)p0 + tid; p < pend; p += BLK) {
        unsigned i = (unsigned)ei[p];
        unsigned j = (unsigned)ej[p];
        int bi = i >> SHIFT;
        int sl = atomicAdd(&curs[bi], 1);
        sR[sl] = j | ((i & (BSZ - 1)) << 20) | (1u << 30);  // owner=i
        sB[sl] = (unsigned char)bi;
        int bj = j >> SHIFT;
        sl = atomicAdd(&curs[bj], 1);
        sR[sl] = i | ((j & (BSZ - 1)) << 20);               // owner=j
        sB[sl] = (unsigned char)bj;
    }
    __syncthreads();

    int total = off[NBPAD - 1] + cnt[NBPAD - 1];
    for (int q = tid; q < total; q += BLK) {
        int b = sB[q];
        int dst = gb[b] + (q - off[b]);
        recs[dst] = sR[q];
    }
}

// ---------------- acc rho ----------------

__global__ __launch_bounds__(BLKA, 8) void eam_acc_rho(
    const unsigned* __restrict__ recs,
    const int* __restrict__ base, const int* __restrict__ counts,
    const float4* __restrict__ pos4t,
    const float* __restrict__ dens_tab, int n_r, int E,
    float inv_dr, float rclip,
    float* __restrict__ partial, int N)
{
    __shared__ float4 sown[BSZ];
    __shared__ float slab[BSZ];
    const int tid = threadIdx.x;
    const int b = blockIdx.x / SSTRIPS;
    const int s = blockIdx.x % SSTRIPS;
    const int abase = b << SHIFT;

    for (int k = tid; k < BSZ; k += BLKA) {
        int a = abase + k;
        sown[k] = (a < N) ? pos4t[a] : make_float4(0.f, 0.f, 0.f, 0.f);
        slab[k] = 0.f;
    }
    __syncthreads();

    int cb = counts[b];
    int e0 = base[b] + (int)(((long long)cb * s) / SSTRIPS);
    int e1 = base[b] + (int)(((long long)cb * (s + 1)) / SSTRIPS);

    for (int q = e0 + tid; q < e1; q += BLKA) {
        unsigned rec = recs[q];
        int other = rec & 0xFFFFF;
        int low = (rec >> 20) & (BSZ - 1);
        float4 w = sown[low];
        float4 o = pos4t[other];
        float dx, dy, dz, r, fr; int i0, i1;
        geom_own(o.x, o.y, o.z, w.x, w.y, w.z, inv_dr, rclip, n_r,
                 dx, dy, dz, r, i0, i1, fr);
        int t_oth = __float_as_int(o.w);

        float v;
        int i0u = __builtin_amdgcn_readfirstlane(i0);
        if (E == 2 && __all(i0 == i0u)) {
            int s1 = min(i0u + 1, n_r - 1);
            float b00 = dens_tab[i0u], b01 = dens_tab[s1];
            float b10 = dens_tab[n_r + i0u], b11 = dens_tab[n_r + s1];
            float e0v = t_oth ? b10 : b00;
            float e1v = t_oth ? b11 : b01;
            v = e0v + fr * (e1v - e0v);
        } else {
            v = interp_row(dens_tab + (size_t)t_oth * n_r, i0, i1, fr);
        }
        lds_fadd(&slab[low], v);
    }
    __syncthreads();

    float* out = partial + ((size_t)(b * SSTRIPS + s) << SHIFT);
    for (int k = tid; k < BSZ; k += BLKA) out[k] = slab[k];
}

// rho = sum strips; dF = F'(rho); pos4f = (x,y,z, dF|type2LSB)
__global__ void eam_reduce_rho_embed_pack(
    const float* __restrict__ partial, const float* __restrict__ pos,
    const int* __restrict__ types,
    const float* __restrict__ embed_tab,
    const float* __restrict__ rho_min_t, const float* __restrict__ inv_drho_t,
    int n_rho, float one_m_eps, float4* __restrict__ pos4f, int N)
{
    int n = blockIdx.x * blockDim.x + threadIdx.x;
    if (n >= N) return;
    int b = n >> SHIFT;
    int low = n & (BSZ - 1);
    float rho = 0.f;
#pragma unroll
    for (int s = 0; s < SSTRIPS; ++s)
        rho += partial[((size_t)(b * SSTRIPS + s) << SHIFT) + low];
    int t = types[n];
    float dF = embed_dF_f(rho, t, embed_tab, rho_min_t, inv_drho_t,
                          n_rho, one_m_eps);
    unsigned u = (__float_as_uint(dF) & ~3u) | ((unsigned)t & 3u);
    float4 v;
    v.x = pos[3 * n + 0];
    v.y = pos[3 * n + 1];
    v.z = pos[3 * n + 2];
    v.w = __uint_as_float(u);
    pos4f[n] = v;
}

// ---------------- acc force ----------------

__global__ __launch_bounds__(BLKA, 8) void eam_acc_force(
    const unsigned* __restrict__ recs,
    const int* __restrict__ base, const int* __restrict__ counts,
    const float4* __restrict__ pos4f,
    const float* __restrict__ dens_deriv_tab,
    const float* __restrict__ pair_deriv_tab,
    int n_r, int E, float inv_dr, float rclip,
    float* __restrict__ partial, int N)
{
    __shared__ float4 sown[BSZ];
    __shared__ float slab[3 * BSZ];
    const int tid = threadIdx.x;
    const int b = blockIdx.x / SSTRIPS;
    const int s = blockIdx.x % SSTRIPS;
    const int abase = b << SHIFT;

    for (int k = tid; k < BSZ; k += BLKA) {
        int a = abase + k;
        sown[k] = (a < N) ? pos4f[a] : make_float4(0.f, 0.f, 0.f, 0.f);
    }
    for (int k = tid; k < 3 * BSZ; k += BLKA) slab[k] = 0.f;
    __syncthreads();

    int cb = counts[b];
    int e0 = base[b] + (int)(((long long)cb * s) / SSTRIPS);
    int e1 = base[b] + (int)(((long long)cb * (s + 1)) / SSTRIPS);

    for (int q = e0 + tid; q < e1; q += BLKA) {
        unsigned rec = recs[q];
        int other  = rec & 0xFFFFF;
        int low    = (rec >> 20) & (BSZ - 1);
        int orient = (rec >> 30) & 1;

        float4 w = sown[low];
        float4 o = pos4f[other];
        int t_oth = (int)(__float_as_uint(o.w) & 3u);
        int t_own = (int)(__float_as_uint(w.w) & 3u);

        float dx, dy, dz, r, fr; int i0, i1;
        geom_own(o.x, o.y, o.z, w.x, w.y, w.z, inv_dr, rclip, n_r,
                 dx, dy, dz, r, i0, i1, fr);

        int prow = orient ? (t_own * E + t_oth) : (t_oth * E + t_own);

        float ddens_oth, ddens_own, dphi;
        int i0u = __builtin_amdgcn_readfirstlane(i0);
        if (E == 2 && __all(i0 == i0u)) {
            int s1 = min(i0u + 1, n_r - 1);
            float a00 = dens_deriv_tab[i0u],       a01 = dens_deriv_tab[s1];
            float a10 = dens_deriv_tab[n_r + i0u], a11 = dens_deriv_tab[n_r + s1];
            float e0o = t_oth ? a10 : a00;
            float e1o = t_oth ? a11 : a01;
            ddens_oth = e0o + fr * (e1o - e0o);
            float e0w = t_own ? a10 : a00;
            float e1w = t_own ? a11 : a01;
            ddens_own = e0w + fr * (e1w - e0w);

            float p00 = pair_deriv_tab[i0u],           p01 = pair_deriv_tab[s1];
            float p10 = pair_deriv_tab[n_r + i0u],     p11 = pair_deriv_tab[n_r + s1];
            float p20 = pair_deriv_tab[2 * n_r + i0u], p21 = pair_deriv_tab[2 * n_r + s1];
            float p30 = pair_deriv_tab[3 * n_r + i0u], p31 = pair_deriv_tab[3 * n_r + s1];
            float q0 = (prow & 2) ? ((prow & 1) ? p30 : p20)
                                  : ((prow & 1) ? p10 : p00);
            float q1 = (prow & 2) ? ((prow & 1) ? p31 : p21)
                                  : ((prow & 1) ? p11 : p01);
            dphi = q0 + fr * (q1 - q0);
        } else {
            ddens_oth = interp_row(dens_deriv_tab + (size_t)t_oth * n_r, i0, i1, fr);
            ddens_own = interp_row(dens_deriv_tab + (size_t)t_own * n_r, i0, i1, fr);
            dphi      = interp_row(pair_deriv_tab + (size_t)prow * n_r, i0, i1, fr);
        }

        float coeff = w.w * ddens_oth + o.w * ddens_own + dphi;

        float fx = -(coeff * (dx / r));
        float fy = -(coeff * (dy / r));
        float fz = -(coeff * (dz / r));

        lds_fadd(&slab[low * 3 + 0], fx);
        lds_fadd(&slab[low * 3 + 1], fy);
        lds_fadd(&slab[low * 3 + 2], fz);
    }
    __syncthreads();

    float* out = partial + (size_t)(b * SSTRIPS + s) * (3 * BSZ);
    for (int k = tid; k < 3 * BSZ; k += BLKA) out[k] = slab[k];
}

__global__ void eam_reduce_force(const float* __restrict__ partial,
                                 float* __restrict__ forces, int N)
{
    int idx = blockIdx.x * blockDim.x + threadIdx.x;
    if (idx >= 3 * N) return;
    int a = idx / 3;
    int comp = idx - 3 * a;
    int b = a >> SHIFT;
    int low = a & (BSZ - 1);
    float s = 0.f;
#pragma unroll
    for (int k = 0; k < SSTRIPS; ++k)
        s += partial[(size_t)(b * SSTRIPS + k) * (3 * BSZ) + low * 3 + comp];
    forces[idx] = s;
}

// ---------------- fallback: direct agent-atomic path ----------------

__device__ __forceinline__ void pair_geom(
    const float* __restrict__ pos, int i, int j,
    float inv_dr, float rclip,
    float& dx, float& dy, float& dz, float& r,
    int& i0, int& i1, float& fr, int n_r)
{
#pragma clang fp contract(off)
    float xi = pos[3 * i + 0], yi = pos[3 * i + 1], zi = pos[3 * i + 2];
    float xj = pos[3 * j + 0], yj = pos[3 * j + 1], zj = pos[3 * j + 2];
    dx = xj - xi; dy = yj - yi; dz = zj - zi;
    float s = dx * dx;
    s = s + dy * dy;
    s = s + dz * dz;
    s = s + 1e-12f;
    r = sqrtf(s);
    float rc = fminf(fmaxf(r, 0.0f), rclip);
    float f  = rc * inv_dr;
    i0 = (int)f;
    fr = f - (float)i0;
    i1 = min(i0 + 1, n_r - 1);
}

__global__ void eam_zero_rho_forces(float* __restrict__ rho,
                                    float* __restrict__ forces, int N) {
    int idx = blockIdx.x * blockDim.x + threadIdx.x;
    if (idx < N) rho[idx] = 0.0f;
    if (idx < 3 * N) forces[idx] = 0.0f;
}

__global__ void eam_density_direct(
    const int* __restrict__ ei, const int* __restrict__ ej,
    const int* __restrict__ types, const float* __restrict__ pos,
    const float* __restrict__ dens_tab, int n_r, float inv_dr, float rclip,
    float* __restrict__ rho, int P)
{
    int p = blockIdx.x * blockDim.x + threadIdx.x;
    if (p >= P) return;
    int i = ei[p], j = ej[p];
    float dx, dy, dz, r, fr; int i0, i1;
    pair_geom(pos, i, j, inv_dr, rclip, dx, dy, dz, r, i0, i1, fr, n_r);
    int ti = types[i], tj = types[j];
    unsafeAtomicAdd(&rho[i], interp_row(dens_tab + (size_t)tj * n_r, i0, i1, fr));
    unsafeAtomicAdd(&rho[j], interp_row(dens_tab + (size_t)ti * n_r, i0, i1, fr));
}

__global__ void eam_force_direct(
    const int* __restrict__ ei, const int* __restrict__ ej,
    const int* __restrict__ types, const float* __restrict__ pos,
    const float* __restrict__ dens_deriv_tab,
    const float* __restrict__ pair_deriv_tab,
    const float* __restrict__ rho,
    const float* __restrict__ embed_tab,
    const float* __restrict__ rho_min_t, const float* __restrict__ inv_drho_t,
    int n_r, int n_rho, int E, float inv_dr, float rclip, float one_m_eps,
    float* __restrict__ forces, int P)
{
    int p = blockIdx.x * blockDim.x + threadIdx.x;
    if (p >= P) return;
    int i = ei[p], j = ej[p];
    float dx, dy, dz, r, fr; int i0, i1;
    pair_geom(pos, i, j, inv_dr, rclip, dx, dy, dz, r, i0, i1, fr, n_r);
    int ti = types[i], tj = types[j];
    float ddens_j = interp_row(dens_deriv_tab + (size_t)tj * n_r, i0, i1, fr);
    float ddens_i = interp_row(dens_deriv_tab + (size_t)ti * n_r, i0, i1, fr);
    float dphi    = interp_row(pair_deriv_tab + ((size_t)ti * E + tj) * n_r, i0, i1, fr);
    float dFi = embed_dF_f(rho[i], ti, embed_tab, rho_min_t, inv_drho_t, n_rho, one_m_eps);
    float dFj = embed_dF_f(rho[j], tj, embed_tab, rho_min_t, inv_drho_t, n_rho, one_m_eps);
    float coeff = dFi * ddens_j + dFj * ddens_i + dphi;
    float fxv = coeff * (dx / r), fyv = coeff * (dy / r), fzv = coeff * (dz / r);
    unsafeAtomicAdd(&forces[3 * i + 0], -fxv);
    unsafeAtomicAdd(&forces[3 * i + 1], -fyv);
    unsafeAtomicAdd(&forces[3 * i + 2], -fzv);
    unsafeAtomicAdd(&forces[3 * j + 0],  fxv);
    unsafeAtomicAdd(&forces[3 * j + 1],  fyv);
    unsafeAtomicAdd(&forces[3 * j + 2],  fzv);
}

// ---------------- launcher ----------------

extern "C" void kernel_launch(void* const* d_in, const int* in_sizes, int n_in,
                              void* d_out, int out_size, void* d_ws, size_t ws_size,
                              hipStream_t stream) {
    const float* positions      = (const float*)d_in[0];
    const float* density_table  = (const float*)d_in[1];
    const float* density_deriv  = (const float*)d_in[2];
    const float* pair_deriv     = (const float*)d_in[3];
    const float* embed_deriv    = (const float*)d_in[4];
    const float* embed_rho_min  = (const float*)d_in[5];
    const float* embed_inv_drho = (const float*)d_in[6];
    const int*   atom_types     = (const int*)d_in[7];
    const int*   edge_i         = (const int*)d_in[8];
    const int*   edge_j         = (const int*)d_in[9];

    const int E     = in_sizes[5];
    const int N     = in_sizes[7];
    const int P     = in_sizes[8];
    const int n_r   = in_sizes[1] / E;
    const int n_rho = in_sizes[4] / E;

    const double R_MAX_d = 6.0;
    const double EPS_d   = 1e-7;
    const float inv_dr    = (float)((double)(n_r - 1) / R_MAX_d);
    const float rclip     = (float)(R_MAX_d * (1.0 - EPS_d));
    const float one_m_eps = (float)(1.0 - EPS_d);

    float* forces = (float*)d_out;

    const int NB = (N + BSZ - 1) >> SHIFT;

    // ws: counts|base|cur | pos4t[N] | pos4f[N] | partials | recs
    char* wp = (char*)d_ws;
    int* counts = (int*)wp;  wp += NBPAD * sizeof(int);
    int* base   = (int*)wp;  wp += NBPAD * sizeof(int);
    int* cur    = (int*)wp;  wp += NBPAD * sizeof(int);
    wp = (char*)(((uintptr_t)wp + 255) & ~(uintptr_t)255);
    float4* pos4t = (float4*)wp; wp += (size_t)N * sizeof(float4);
    float4* pos4f = (float4*)wp; wp += (size_t)N * sizeof(float4);
    float* partials = (float*)wp; wp += (size_t)NB * SSTRIPS * 3 * BSZ * sizeof(float);
    unsigned* recs = (unsigned*)wp; wp += 2 * (size_t)P * sizeof(unsigned);
    const size_t need = (size_t)(wp - (char*)d_ws);

    const int pair_blocks = (P + BLK - 1) / BLK;
    const int atom_blocks = (N + BLK - 1) / BLK;

    if (need > ws_size || NB > NBPAD || N >= (1 << 20) || E > 4) {
        float* rho_f = (float*)d_ws;
        eam_zero_rho_forces<<<(3 * N + BLK - 1) / BLK, BLK, 0, stream>>>(rho_f, forces, N);
        eam_density_direct<<<pair_blocks, BLK, 0, stream>>>(
            edge_i, edge_j, atom_types, positions,
            density_table, n_r, inv_dr, rclip, rho_f, P);
        eam_force_direct<<<pair_blocks, BLK, 0, stream>>>(
            edge_i, edge_j, atom_types, positions,
            density_deriv, pair_deriv, rho_f,
            embed_deriv, embed_rho_min, embed_inv_drho,
            n_r, n_rho, E, inv_dr, rclip, one_m_eps, forces, P);
        return;
    }

    eam_zero_meta<<<1, NBPAD, 0, stream>>>(counts);
    eam_count<<<512, BLK, 0, stream>>>(edge_i, edge_j, P, counts);
    eam_scan<<<1, NBPAD, 0, stream>>>(counts, base, cur);
    eam_build_pos4t<<<atom_blocks, BLK, 0, stream>>>(positions, atom_types, pos4t, N);

    eam_bin<<<(P + PPB_B - 1) / PPB_B, BLK, 0, stream>>>(
        edge_i, edge_j, P, cur, recs);

    eam_acc_rho<<<NB * SSTRIPS, BLKA, 0, stream>>>(
        recs, base, counts, pos4t,
        density_table, n_r, E, inv_dr, rclip, partials, N);

    eam_reduce_rho_embed_pack<<<atom_blocks, BLK, 0, stream>>>(
        partials, positions, atom_types,
        embed_deriv, embed_rho_min, embed_inv_drho,
        n_rho, one_m_eps, pos4f, N);

    eam_acc_force<<<NB * SSTRIPS, BLKA, 0, stream>>>(
        recs, base, counts, pos4f,
        density_deriv, pair_deriv,
        n_r, E, inv_dr, rclip, partials, N);

    eam_reduce_force<<<(3 * N + BLK - 1) / BLK, BLK, 0, stream>>>(
        partials, forces, N);
}